// Round 1
// baseline (350.155 us; speedup 1.0000x reference)
//
#include <hip/hip_runtime.h>

#define DIM 32
#define BLOCK 256

// One thread = one row of the (B, 32) state.
// Gibbs step i:  x_i <- mu_i - (sum_{j!=i} P[i][j] x_j)/P[i][i] + sqrt(1/P[i][i]) * n_i
// Folded:        x_i <- m[i] + sum_j c[i][j] x_j + s[i] * n_i
//   with c[i][j] = -P[i][j]/P[i][i] (j != i), c[i][i] = 0, s[i] = sqrt(1/P[i][i]).
__global__ __launch_bounds__(BLOCK) void gibbs_sweep_kernel(
    const float* __restrict__ x,
    const float* __restrict__ noise,
    const float* __restrict__ prec,
    const float* __restrict__ mu,
    float* __restrict__ out)
{
    __shared__ float c_lds[DIM * DIM];  // 4 KB coefficient table (uniform-address broadcast reads)
    __shared__ float s_lds[DIM];
    __shared__ float m_lds[DIM];

    const int t = threadIdx.x;

    // Precompute folded coefficients (redundantly per block; prec is 4 KB, L2/L3-resident).
    // 1024 entries / 256 threads = 4 each.
#pragma unroll
    for (int k = 0; k < 4; ++k) {
        const int idx = t * 4 + k;
        const int i = idx >> 5;
        const int j = idx & 31;
        const float pii = prec[i * DIM + i];
        c_lds[idx] = (j == i) ? 0.0f : (-prec[idx] / pii);
    }
    if (t < DIM) {
        const float pii = prec[t * DIM + t];
        s_lds[t] = sqrtf(1.0f / pii);
        m_lds[t] = mu[t];
    }
    __syncthreads();

    const long row = (long)blockIdx.x * BLOCK + t;
    const float4* __restrict__ xp = (const float4*)(x + row * DIM);
    const float4* __restrict__ np4 = (const float4*)(noise + row * DIM);
    float4* __restrict__ op = (float4*)(out + row * DIM);

    // Load this thread's row (one 128-B cache line) + noise row into registers.
    float xr[DIM];
    float nr[DIM];
#pragma unroll
    for (int k = 0; k < DIM / 4; ++k) {
        const float4 v = xp[k];
        xr[k * 4 + 0] = v.x; xr[k * 4 + 1] = v.y;
        xr[k * 4 + 2] = v.z; xr[k * 4 + 3] = v.w;
        const float4 n = np4[k];
        nr[k * 4 + 0] = n.x; nr[k * 4 + 1] = n.y;
        nr[k * 4 + 2] = n.z; nr[k * 4 + 3] = n.w;
    }

    const float4* __restrict__ c4 = (const float4*)c_lds;

    // Sequential sweep over 32 coordinates; dot over 32 regs, 4 partial accumulators.
#pragma unroll
    for (int i = 0; i < DIM; ++i) {
        float a0 = m_lds[i];
        float a1 = 0.0f, a2 = 0.0f, a3 = 0.0f;
#pragma unroll
        for (int k = 0; k < DIM / 4; k += 4) {
            const float4 c0 = c4[i * 8 + k + 0];
            const float4 c1 = c4[i * 8 + k + 1];
            const float4 c2 = c4[i * 8 + k + 2];
            const float4 c3 = c4[i * 8 + k + 3];
            a0 += c0.x * xr[(k + 0) * 4 + 0] + c0.y * xr[(k + 0) * 4 + 1]
                + c0.z * xr[(k + 0) * 4 + 2] + c0.w * xr[(k + 0) * 4 + 3];
            a1 += c1.x * xr[(k + 1) * 4 + 0] + c1.y * xr[(k + 1) * 4 + 1]
                + c1.z * xr[(k + 1) * 4 + 2] + c1.w * xr[(k + 1) * 4 + 3];
            a2 += c2.x * xr[(k + 2) * 4 + 0] + c2.y * xr[(k + 2) * 4 + 1]
                + c2.z * xr[(k + 2) * 4 + 2] + c2.w * xr[(k + 2) * 4 + 3];
            a3 += c3.x * xr[(k + 3) * 4 + 0] + c3.y * xr[(k + 3) * 4 + 1]
                + c3.z * xr[(k + 3) * 4 + 2] + c3.w * xr[(k + 3) * 4 + 3];
        }
        xr[i] = ((a0 + a1) + (a2 + a3)) + s_lds[i] * nr[i];
    }

    // Store the updated row.
#pragma unroll
    for (int k = 0; k < DIM / 4; ++k) {
        op[k] = make_float4(xr[k * 4 + 0], xr[k * 4 + 1],
                            xr[k * 4 + 2], xr[k * 4 + 3]);
    }
}

extern "C" void kernel_launch(void* const* d_in, const int* in_sizes, int n_in,
                              void* d_out, int out_size, void* d_ws, size_t ws_size,
                              hipStream_t stream) {
    const float* x     = (const float*)d_in[0];  // (B, 32)
    const float* noise = (const float*)d_in[1];  // (B, 32)
    const float* prec  = (const float*)d_in[2];  // (32, 32)
    const float* mu    = (const float*)d_in[3];  // (32,)
    float* out = (float*)d_out;

    const int B = in_sizes[0] / DIM;             // 1048576
    const int grid = B / BLOCK;                  // 4096 blocks

    gibbs_sweep_kernel<<<grid, BLOCK, 0, stream>>>(x, noise, prec, mu, out);
}

// Round 2
// 324.633 us; speedup vs baseline: 1.0786x; 1.0786x over previous
//
#include <hip/hip_runtime.h>

#define DIM 32
#define BLOCK 256

// d_ws layout: c[32][32] folded coefficients, then s[32], then m[32]  (1088 floats)
//   c[i][j] = -P[i][j]/P[i][i]  (j != i),  c[i][i] = 0
//   s[i]    = sqrt(1/P[i][i])
//   m[i]    = mu[i]
__global__ __launch_bounds__(256) void gibbs_setup_kernel(
    const float* __restrict__ prec,
    const float* __restrict__ mu,
    float* __restrict__ ws)
{
    const int t = threadIdx.x;
#pragma unroll
    for (int k = 0; k < 4; ++k) {
        const int idx = t * 4 + k;
        const int i = idx >> 5;
        const int j = idx & 31;
        const float pii = prec[i * DIM + i];
        ws[idx] = (j == i) ? 0.0f : (-prec[idx] / pii);
    }
    if (t < DIM) {
        const float pii = prec[t * DIM + t];
        ws[1024 + t] = sqrtf(1.0f / pii);
        ws[1056 + t] = mu[t];
    }
}

// Dot of the (wave-uniform, SGPR-resident) coefficient row with the 32
// register-resident x values. Grouped into 4 chains of 8 so the FP add
// dependency depth stays ~8 FMAs.
#define DOT32(C) \
  ( ( ((C)[0]*x0   + (C)[1]*x1   + (C)[2]*x2   + (C)[3]*x3   \
     + (C)[4]*x4   + (C)[5]*x5   + (C)[6]*x6   + (C)[7]*x7)  \
    + ((C)[8]*x8   + (C)[9]*x9   + (C)[10]*x10 + (C)[11]*x11 \
     + (C)[12]*x12 + (C)[13]*x13 + (C)[14]*x14 + (C)[15]*x15) ) \
  + ( ((C)[16]*x16 + (C)[17]*x17 + (C)[18]*x18 + (C)[19]*x19 \
     + (C)[20]*x20 + (C)[21]*x21 + (C)[22]*x22 + (C)[23]*x23) \
    + ((C)[24]*x24 + (C)[25]*x25 + (C)[26]*x26 + (C)[27]*x27 \
     + (C)[28]*x28 + (C)[29]*x29 + (C)[30]*x30 + (C)[31]*x31) ) )

#define STEP(i) { \
    const float* __restrict__ ci = cw + (i) * 32; \
    x##i = fmaf(sw[(i)], n##i, mw[(i)] + DOT32(ci)); }

// One thread = one row. x/noise in named scalar registers; coefficients come
// in through scalar loads (uniform addresses) -> v_fmac with SGPR operand.
__global__ __launch_bounds__(BLOCK, 4) void gibbs_sweep_kernel(
    const float* __restrict__ x,
    const float* __restrict__ noise,
    const float* __restrict__ ws,
    float* __restrict__ out)
{
    const float* __restrict__ cw = ws;          // 32x32 folded coefficients
    const float* __restrict__ sw = ws + 1024;   // sqrt(1/Pii)
    const float* __restrict__ mw = ws + 1056;   // mu

    const long row = (long)blockIdx.x * BLOCK + threadIdx.x;
    const float4* __restrict__ xp  = (const float4*)(x + row * DIM);
    const float4* __restrict__ np4 = (const float4*)(noise + row * DIM);
    float4* __restrict__ op = (float4*)(out + row * DIM);

    float x0,x1,x2,x3,x4,x5,x6,x7,x8,x9,x10,x11,x12,x13,x14,x15,
          x16,x17,x18,x19,x20,x21,x22,x23,x24,x25,x26,x27,x28,x29,x30,x31;
    float n0,n1,n2,n3,n4,n5,n6,n7,n8,n9,n10,n11,n12,n13,n14,n15,
          n16,n17,n18,n19,n20,n21,n22,n23,n24,n25,n26,n27,n28,n29,n30,n31;

    {
        float4 u;
        u = xp[0]; x0 = u.x; x1 = u.y; x2 = u.z; x3 = u.w;
        u = xp[1]; x4 = u.x; x5 = u.y; x6 = u.z; x7 = u.w;
        u = xp[2]; x8 = u.x; x9 = u.y; x10 = u.z; x11 = u.w;
        u = xp[3]; x12 = u.x; x13 = u.y; x14 = u.z; x15 = u.w;
        u = xp[4]; x16 = u.x; x17 = u.y; x18 = u.z; x19 = u.w;
        u = xp[5]; x20 = u.x; x21 = u.y; x22 = u.z; x23 = u.w;
        u = xp[6]; x24 = u.x; x25 = u.y; x26 = u.z; x27 = u.w;
        u = xp[7]; x28 = u.x; x29 = u.y; x30 = u.z; x31 = u.w;
        u = np4[0]; n0 = u.x; n1 = u.y; n2 = u.z; n3 = u.w;
        u = np4[1]; n4 = u.x; n5 = u.y; n6 = u.z; n7 = u.w;
        u = np4[2]; n8 = u.x; n9 = u.y; n10 = u.z; n11 = u.w;
        u = np4[3]; n12 = u.x; n13 = u.y; n14 = u.z; n15 = u.w;
        u = np4[4]; n16 = u.x; n17 = u.y; n18 = u.z; n19 = u.w;
        u = np4[5]; n20 = u.x; n21 = u.y; n22 = u.z; n23 = u.w;
        u = np4[6]; n24 = u.x; n25 = u.y; n26 = u.z; n27 = u.w;
        u = np4[7]; n28 = u.x; n29 = u.y; n30 = u.z; n31 = u.w;
    }

    STEP(0)  STEP(1)  STEP(2)  STEP(3)  STEP(4)  STEP(5)  STEP(6)  STEP(7)
    STEP(8)  STEP(9)  STEP(10) STEP(11) STEP(12) STEP(13) STEP(14) STEP(15)
    STEP(16) STEP(17) STEP(18) STEP(19) STEP(20) STEP(21) STEP(22) STEP(23)
    STEP(24) STEP(25) STEP(26) STEP(27) STEP(28) STEP(29) STEP(30) STEP(31)

    op[0] = make_float4(x0,  x1,  x2,  x3);
    op[1] = make_float4(x4,  x5,  x6,  x7);
    op[2] = make_float4(x8,  x9,  x10, x11);
    op[3] = make_float4(x12, x13, x14, x15);
    op[4] = make_float4(x16, x17, x18, x19);
    op[5] = make_float4(x20, x21, x22, x23);
    op[6] = make_float4(x24, x25, x26, x27);
    op[7] = make_float4(x28, x29, x30, x31);
}

extern "C" void kernel_launch(void* const* d_in, const int* in_sizes, int n_in,
                              void* d_out, int out_size, void* d_ws, size_t ws_size,
                              hipStream_t stream) {
    const float* x     = (const float*)d_in[0];  // (B, 32)
    const float* noise = (const float*)d_in[1];  // (B, 32)
    const float* prec  = (const float*)d_in[2];  // (32, 32)
    const float* mu    = (const float*)d_in[3];  // (32,)
    float* out = (float*)d_out;
    float* ws  = (float*)d_ws;                   // needs 1088 floats (4.25 KB)

    const int B = in_sizes[0] / DIM;             // 1048576
    const int grid = B / BLOCK;                  // 4096 blocks

    gibbs_setup_kernel<<<1, 256, 0, stream>>>(prec, (const float*)d_in[3], ws);
    gibbs_sweep_kernel<<<grid, BLOCK, 0, stream>>>(x, noise, ws, out);
}